// Round 11
// baseline (414.386 us; speedup 1.0000x reference)
//
#include <hip/hip_runtime.h>
#include <stdint.h>

// ResBlock: GraphConv(64->128) -> BN -> ReLU -> GraphConv(128->128) -> BN
//           + (x @ Wlin^T + blin) residual -> ReLU.
// Runtime dtype probe (bf16 vs f32).
// R19: FUSE agg1+gemm1 -> k_ag1. agg1 (59.4us, memory-path-bound, VALU
// half-idle) and gemm1 (63.5us, latency-bound, memory idle) have
// complementary idle resources and a row-for-row producer/consumer
// relationship. Fused: per 64-row chunk, 4 waves gather 16 nodes each
// (agg1's 4-slot/4-deep pattern) into LDS (stride 130, mirrors the
// measured-zero-conflict 258 layout), barrier, then the proven MFMA phase
// with A = [y0p direct-global | agg from LDS]. Kills the 25MB agg round
// trip + one launch; gemm compute hides under the gather's 177MB.
// R18 base (385us): xb bf16, direct-global gemm0, persistent G=1024,
// prep/fill2 fusions, PSH=8, register BN stats, y0p pass.

#define CIN 64
#define COUT 128
#define BN_EPS 1e-5f
#define CURPAD 32              // ints: one 128B line per cursor
#define PCPAD 32               // ints: one 128B line per pcount entry
#define SPAD 32                // floats: one 128B line per stats channel
#define PSH 8                  // partition = dst >> PSH  (256 nodes)
#define PNODES (1 << PSH)
#define MAXP 512               // supports N <= 131072

typedef unsigned short u16;
typedef short short8 __attribute__((ext_vector_type(8)));
typedef float f32x4 __attribute__((ext_vector_type(4)));

__device__ __forceinline__ float bf2f(u16 u) {
    union { unsigned int i; float f; } v; v.i = ((unsigned int)u) << 16; return v.f;
}
__device__ __forceinline__ u16 f2bf(float f) {
    union { float f; unsigned int i; } v; v.f = f;
    unsigned int r = v.i + 0x7fffu + ((v.i >> 16) & 1u);  // RNE; finite inputs
    return (u16)(r >> 16);
}
__device__ __forceinline__ float lo16(unsigned int w) { return bf2f((u16)(w & 0xffffu)); }
__device__ __forceinline__ float hi16(unsigned int w) { return bf2f((u16)(w >> 16)); }

template<bool BF> __device__ __forceinline__ float ldf(const void* p, long i) {
    if (BF) return bf2f(((const u16*)p)[i]);
    return ((const float*)p)[i];
}
template<bool BF> __device__ __forceinline__ short8 ld8(const void* p, long i) {
    if (BF) return *(const short8*)((const u16*)p + i);
    const float* f = (const float*)p + i;
    short8 r;
#pragma unroll
    for (int j = 0; j < 8; ++j) r[j] = (short)f2bf(f[j]);
    return r;
}

__device__ __forceinline__ void acc8(float* a, uint4 w) {
    a[0] += lo16(w.x); a[1] += hi16(w.x);
    a[2] += lo16(w.y); a[3] += hi16(w.y);
    a[4] += lo16(w.z); a[5] += hi16(w.z);
    a[6] += lo16(w.w); a[7] += hi16(w.w);
}

// ---- K1: fused dtype-detect (block 0) + partition histogram (rest) ------
__global__ __launch_bounds__(256) void k_prep(const unsigned int* __restrict__ x,
        int* __restrict__ flag, const int* __restrict__ dst,
        int* __restrict__ pcount, int E, int np) {
    if (blockIdx.x == 0) {
        if (threadIdx.x < 64) {
            int lane = threadIdx.x;
            int cnt = 0;
#pragma unroll
            for (int i = 0; i < 8; ++i) {
                unsigned int w = x[lane * 8 + i];
                unsigned int e0 = (w >> 7) & 0xFFu, e1 = (w >> 23) & 0xFFu;
                cnt += (e0 >= 0x60u && e0 <= 0x8Eu);
                cnt += (e1 >= 0x60u && e1 <= 0x8Eu);
            }
            for (int o = 32; o; o >>= 1) cnt += __shfl_down(cnt, o);
            if (lane == 0) *flag = (cnt > 850) ? 1 : 0;   // 1 => bf16
        }
        return;
    }
    __shared__ int h[MAXP];
    int bid = blockIdx.x - 1;
    int nb = gridDim.x - 1;
    for (int i = threadIdx.x; i < np; i += 256) h[i] = 0;
    __syncthreads();
    int stride = nb * 256;
    for (int e = bid * 256 + threadIdx.x; e < E; e += stride)
        atomicAdd(&h[dst[e] >> PSH], 1);
    __syncthreads();
    for (int i = threadIdx.x; i < np; i += 256)
        if (h[i]) atomicAdd(&pcount[i * PCPAD], h[i]);
}

__global__ void k_pscan(const int* __restrict__ pcount, int* __restrict__ pstart,
                        int* __restrict__ pcursor, int np, int E) {
    __shared__ int s[MAXP];
    int t = threadIdx.x;  // MAXP threads
    int v = (t < np) ? pcount[t * PCPAD] : 0;
    s[t] = v; __syncthreads();
    for (int o = 1; o < MAXP; o <<= 1) {
        int u = (t >= o) ? s[t - o] : 0;
        __syncthreads(); s[t] += u; __syncthreads();
    }
    if (t < np) {
        int ex = s[t] - v;
        pstart[t] = ex;
        pcursor[t * CURPAD] = ex;
    }
    if (t == 0) pstart[np] = E;
}

// ---- K3: fused pfill (blocks < ntl) + xbf stream (blocks >= ntl) --------
__global__ __launch_bounds__(256) void k_fill2(const int* __restrict__ src,
        const int* __restrict__ dst, int* __restrict__ pcursor,
        unsigned int* __restrict__ barr, int E, int np, int ntl,
        const int* __restrict__ flag, const void* __restrict__ x,
        u16* __restrict__ xb, long n8) {
    __shared__ int cnt[MAXP], gb[MAXP], loc[MAXP];
    int tid = threadIdx.x;
    if (blockIdx.x >= ntl) {
        // ---- xbf part: xb = bf16(x) ----
        int nb = gridDim.x - ntl;
        long idx = (long)(blockIdx.x - ntl) * 256 + tid;
        long stride = (long)nb * 256;
        uint4* d4 = (uint4*)xb;
        if (*flag) {
            const uint4* s4 = (const uint4*)x;
            for (; idx < n8; idx += stride) d4[idx] = s4[idx];
        } else {
            const float4* s4 = (const float4*)x;
            for (; idx < n8; idx += stride) {
                float4 a = s4[idx * 2], b = s4[idx * 2 + 1];
                uint4 o;
                o.x = (unsigned int)f2bf(a.x) | ((unsigned int)f2bf(a.y) << 16);
                o.y = (unsigned int)f2bf(a.z) | ((unsigned int)f2bf(a.w) << 16);
                o.z = (unsigned int)f2bf(b.x) | ((unsigned int)f2bf(b.y) << 16);
                o.w = (unsigned int)f2bf(b.z) | ((unsigned int)f2bf(b.w) << 16);
                d4[idx] = o;
            }
        }
        return;
    }
    // ---- pfill part: rec = (dst & (PNODES-1)) << 20 | src ----
    int base = blockIdx.x * 4096;
    for (int i = tid; i < np; i += 256) { cnt[i] = 0; loc[i] = 0; }
    __syncthreads();
    int pk[16]; unsigned int rec[16];
#pragma unroll
    for (int k = 0; k < 16; ++k) {
        int e = base + k * 256 + tid;
        if (e < E) {
            int d = dst[e];
            pk[k] = d >> PSH;
            rec[k] = ((unsigned int)(d & (PNODES - 1)) << 20) | (unsigned int)src[e];
            atomicAdd(&cnt[pk[k]], 1);
        } else pk[k] = -1;
    }
    __syncthreads();
    for (int i = tid; i < np; i += 256)
        if (cnt[i]) gb[i] = atomicAdd(&pcursor[i * CURPAD], cnt[i]);
    __syncthreads();
#pragma unroll
    for (int k = 0; k < 16; ++k) {
        if (pk[k] >= 0) {
            int off = atomicAdd(&loc[pk[k]], 1);
            barr[gb[pk[k]] + off] = rec[k];
        }
    }
}

// Block per partition (PNODES=256): LDS counting sort -> csr + row_start.
__global__ __launch_bounds__(256) void k_psort(const unsigned int* __restrict__ barr,
        const int* __restrict__ pstart, int* __restrict__ csr,
        int* __restrict__ row_start, int n, int np, int E) {
    __shared__ int hist[PNODES], curs[PNODES], tsum[256];
    int tid = threadIdx.x;
    int p = blockIdx.x;
    int e0 = pstart[p], e1 = pstart[p + 1];
    int node0 = p << PSH;
    hist[tid] = 0;
    __syncthreads();
    for (int t = e0 + tid; t < e1; t += 256)
        atomicAdd(&hist[barr[t] >> 20], 1);
    __syncthreads();
    int v = hist[tid];
    tsum[tid] = v; __syncthreads();
    for (int o = 1; o < 256; o <<= 1) {
        int u = (tid >= o) ? tsum[tid - o] : 0;
        __syncthreads(); tsum[tid] += u; __syncthreads();
    }
    int ex = tsum[tid] - v;
    curs[tid] = ex;
    int nd = node0 + tid;
    if (nd < n) row_start[nd] = e0 + ex;
    if (p == np - 1 && tid == 0) row_start[n] = E;
    __syncthreads();
    for (int t = e0 + tid; t < e1; t += 256) {
        unsigned int rec = barr[t];
        int pos = atomicAdd(&curs[rec >> 20], 1);
        csr[e0 + pos] = (int)(rec & 0xFFFFF);
    }
}

// ---- aggregation 0: bf16 gather on xb rows (128B), 4-deep batches -------
__global__ __launch_bounds__(256) void k_agg0(const u16* __restrict__ xb,
        const int* __restrict__ rs, const int* __restrict__ csr,
        u16* __restrict__ agg, int n) {
    int i = blockIdx.x * 4 + (threadIdx.x >> 6);
    if (i >= n) return;
    int lane = threadIdx.x & 63;
    int slot = lane >> 4, cp = lane & 15;   // xb row = 128B = 16 x uint2
    const unsigned int* x32 = (const unsigned int*)xb;
    int b = rs[i], e = rs[i + 1];
    float acc[4] = {0.f, 0.f, 0.f, 0.f};
    int t = b + slot;
    for (; t + 12 < e; t += 16) {
        int j0 = csr[t], j1 = csr[t + 4], j2 = csr[t + 8], j3 = csr[t + 12];
        uint2 w0 = *((const uint2*)(x32 + (long)j0 * 32) + cp);
        uint2 w1 = *((const uint2*)(x32 + (long)j1 * 32) + cp);
        uint2 w2 = *((const uint2*)(x32 + (long)j2 * 32) + cp);
        uint2 w3 = *((const uint2*)(x32 + (long)j3 * 32) + cp);
        acc[0] += lo16(w0.x) + lo16(w1.x); acc[1] += hi16(w0.x) + hi16(w1.x);
        acc[2] += lo16(w0.y) + lo16(w1.y); acc[3] += hi16(w0.y) + hi16(w1.y);
        acc[0] += lo16(w2.x) + lo16(w3.x); acc[1] += hi16(w2.x) + hi16(w3.x);
        acc[2] += lo16(w2.y) + lo16(w3.y); acc[3] += hi16(w2.y) + hi16(w3.y);
    }
    for (; t < e; t += 4) {
        int j0 = csr[t];
        uint2 w0 = *((const uint2*)(x32 + (long)j0 * 32) + cp);
        acc[0] += lo16(w0.x); acc[1] += hi16(w0.x);
        acc[2] += lo16(w0.y); acc[3] += hi16(w0.y);
    }
#pragma unroll
    for (int k = 0; k < 4; ++k) {
        acc[k] += __shfl_xor(acc[k], 16);
        acc[k] += __shfl_xor(acc[k], 32);
    }
    if (slot == 0) {
        uint2 o;
        o.x = (unsigned int)f2bf(acc[0]) | ((unsigned int)f2bf(acc[1]) << 16);
        o.y = (unsigned int)f2bf(acc[2]) | ((unsigned int)f2bf(acc[3]) << 16);
        *((uint2*)((unsigned int*)agg + (long)i * 32) + cp) = o;
    }
}

// ---- y0p = relu(bn0(y0)) materialized IN-PLACE (bf16), streaming --------
__global__ __launch_bounds__(256) void k_y0p(unsigned int* __restrict__ y0,
        const float* __restrict__ sc, const float* __restrict__ sh, long nq) {
    long idx = (long)blockIdx.x * 256 + threadIdx.x;
    int colq = threadIdx.x & 15;
    float s8[8], h8[8];
#pragma unroll
    for (int j = 0; j < 8; ++j) { s8[j] = sc[colq * 8 + j]; h8[j] = sh[colq * 8 + j]; }
    long stride = (long)gridDim.x * 256;
    uint4* p = (uint4*)y0;
    for (; idx < nq; idx += stride) {
        uint4 w = p[idx];
        unsigned int r[4] = {w.x, w.y, w.z, w.w};
        uint4 o;
        unsigned int* po = (unsigned int*)&o;
#pragma unroll
        for (int d = 0; d < 4; ++d) {
            float a = fmaxf(lo16(r[d]) * s8[2 * d]     + h8[2 * d],     0.f);
            float b = fmaxf(hi16(r[d]) * s8[2 * d + 1] + h8[2 * d + 1], 0.f);
            po[d] = (unsigned int)f2bf(a) | ((unsigned int)f2bf(b) << 16);
        }
        p[idx] = o;
    }
}

// ------ GEMM0 (direct-global, persistent): y0 = [xb|agg0] @ W0^T ----------
template<bool BF>
__device__ __forceinline__ void gemm0_impl(const u16* xb, const u16* agg,
                                           const void* Wr, const void* Wn,
                                           u16* y0, float* sumP, float* sqP,
                                           int n, int nch) {
    int tid = threadIdx.x;
    int wave = tid >> 6, lane = tid & 63, lr = lane & 15, q = lane >> 4;

    short8 wf[2][4];
#pragma unroll
    for (int i = 0; i < 2; ++i) {
        int c = (2 * wave + i) * 16 + lr;
#pragma unroll
        for (int ks = 0; ks < 4; ++ks) {
            const void* W = (ks < 2) ? Wr : Wn;
            wf[i][ks] = ld8<BF>(W, (long)c * CIN + (ks & 1) * 32 + q * 8);
        }
    }

    float st[2] = {0.f, 0.f}, sq[2] = {0.f, 0.f};
    for (int ch = blockIdx.x; ch < nch; ch += gridDim.x) {
        long chunk0 = (long)ch * 64;
#pragma unroll
        for (int t = 0; t < 4; ++t) {
            long rg = chunk0 + t * 16 + lr; if (rg > n - 1) rg = n - 1;
            short8 a[4];
#pragma unroll
            for (int ks = 0; ks < 2; ++ks)
                a[ks] = *(const short8*)(xb + rg * CIN + ks * 32 + q * 8);
#pragma unroll
            for (int ks = 0; ks < 2; ++ks)
                a[2 + ks] = *(const short8*)(agg + rg * CIN + ks * 32 + q * 8);
#pragma unroll
            for (int i = 0; i < 2; ++i) {
                f32x4 acc = {0.f, 0.f, 0.f, 0.f};
#pragma unroll
                for (int ks = 0; ks < 4; ++ks)
                    acc = __builtin_amdgcn_mfma_f32_16x16x32_bf16(a[ks], wf[i][ks], acc, 0, 0, 0);
                int c = (2 * wave + i) * 16 + lr;
#pragma unroll
                for (int r = 0; r < 4; ++r) {
                    long row = chunk0 + t * 16 + q * 4 + r;
                    if (row < n) {
                        y0[row * COUT + c] = f2bf(acc[r]);   // b0 cancels in BN
                        st[i] += acc[r]; sq[i] += acc[r] * acc[r];
                    }
                }
            }
        }
    }
#pragma unroll
    for (int i = 0; i < 2; ++i) {
        st[i] += __shfl_xor(st[i], 16); st[i] += __shfl_xor(st[i], 32);
        sq[i] += __shfl_xor(sq[i], 16); sq[i] += __shfl_xor(sq[i], 32);
    }
    if (q == 0) {
#pragma unroll
        for (int i = 0; i < 2; ++i) {
            int c = (2 * wave + i) * 16 + lr;
            atomicAdd(&sumP[c * SPAD], st[i]);
            atomicAdd(&sqP[c * SPAD], sq[i]);
        }
    }
}

__global__ __launch_bounds__(256) void k_gemm0(const int* __restrict__ flag,
        const u16* __restrict__ xb, const u16* __restrict__ agg,
        const void* Wr, const void* Wn,
        u16* __restrict__ y0, float* __restrict__ sumP, float* __restrict__ sqP,
        int n, int nch) {
    if (*flag) gemm0_impl<true >(xb, agg, Wr, Wn, y0, sumP, sqP, n, nch);
    else       gemm0_impl<false>(xb, agg, Wr, Wn, y0, sumP, sqP, n, nch);
}

// ------ FUSED agg1+gemm1: y1 = [y0p | gather(y0p)] @ W1^T, stats ----------
// Per 64-row chunk: 4 waves each gather 16 nodes' neighbor sums (4-slot x
// 4-deep, same as old agg1) into LDS; barrier; MFMA with A = [y0p global |
// agg LDS]. Kills the agg global round trip; gemm hides under gather.
template<bool BF>
__device__ __forceinline__ void ag1_impl(const u16* y0p,
                                         const int* __restrict__ rs,
                                         const int* __restrict__ csr,
                                         const void* Wr, const void* Wn,
                                         u16* y1, float* sumP, float* sqP,
                                         int n, int nch, u16* lds) {
    const int ST = 130;                 // 64 x 130 u16 LDS agg tile
    int tid = threadIdx.x;
    int wave = tid >> 6, lane = tid & 63, lr = lane & 15, q = lane >> 4;
    int slot = lane >> 4, cp = lane & 15;
    const unsigned int* y32 = (const unsigned int*)y0p;

    short8 wf[2][8];
#pragma unroll
    for (int i = 0; i < 2; ++i) {
        int c = (2 * wave + i) * 16 + lr;
#pragma unroll
        for (int ks = 0; ks < 8; ++ks) {
            const void* W = (ks < 4) ? Wr : Wn;
            wf[i][ks] = ld8<BF>(W, (long)c * COUT + (ks & 3) * 32 + q * 8);
        }
    }

    float st[2] = {0.f, 0.f}, sq[2] = {0.f, 0.f};
    for (int ch = blockIdx.x; ch < nch; ch += gridDim.x) {
        long chunk0 = (long)ch * 64;
        __syncthreads();                // prev MFMA done with LDS
        // ---- gather phase: wave handles rows wave*16 .. wave*16+15 ----
        for (int j = 0; j < 16; ++j) {
            int li = wave * 16 + j;
            long node = chunk0 + li;
            float acc[8] = {0.f, 0.f, 0.f, 0.f, 0.f, 0.f, 0.f, 0.f};
            if (node < n) {
                int b = rs[node], e = rs[node + 1];
                int t = b + slot;
                for (; t + 12 < e; t += 16) {
                    int j0 = csr[t], j1 = csr[t + 4], j2 = csr[t + 8], j3 = csr[t + 12];
                    uint4 w0 = *((const uint4*)(y32 + (long)j0 * 64) + cp);
                    uint4 w1 = *((const uint4*)(y32 + (long)j1 * 64) + cp);
                    uint4 w2 = *((const uint4*)(y32 + (long)j2 * 64) + cp);
                    uint4 w3 = *((const uint4*)(y32 + (long)j3 * 64) + cp);
                    acc8(acc, w0); acc8(acc, w1); acc8(acc, w2); acc8(acc, w3);
                }
                for (; t < e; t += 4) {
                    uint4 w0 = *((const uint4*)(y32 + (long)csr[t] * 64) + cp);
                    acc8(acc, w0);
                }
            }
#pragma unroll
            for (int k = 0; k < 8; ++k) {
                acc[k] += __shfl_xor(acc[k], 16);
                acc[k] += __shfl_xor(acc[k], 32);
            }
            if (slot == 0) {
                short8 o;
#pragma unroll
                for (int k = 0; k < 8; ++k) o[k] = (short)f2bf(acc[k]);
                *(short8*)(lds + li * ST + cp * 8) = o;
            }
        }
        __syncthreads();
        // ---- MFMA phase: A = [y0p global | agg LDS] ----
#pragma unroll
        for (int t = 0; t < 4; ++t) {
            long rg = chunk0 + t * 16 + lr; if (rg > n - 1) rg = n - 1;
            short8 a[8];
#pragma unroll
            for (int ks = 0; ks < 4; ++ks)
                a[ks] = *(const short8*)(y0p + rg * COUT + ks * 32 + q * 8);
#pragma unroll
            for (int ks = 0; ks < 4; ++ks)
                a[4 + ks] = *(const short8*)(lds + (t * 16 + lr) * ST + ks * 32 + q * 8);
#pragma unroll
            for (int i = 0; i < 2; ++i) {
                f32x4 acc = {0.f, 0.f, 0.f, 0.f};
#pragma unroll
                for (int ks = 0; ks < 8; ++ks)
                    acc = __builtin_amdgcn_mfma_f32_16x16x32_bf16(a[ks], wf[i][ks], acc, 0, 0, 0);
                int c = (2 * wave + i) * 16 + lr;
#pragma unroll
                for (int r = 0; r < 4; ++r) {
                    long row = chunk0 + t * 16 + q * 4 + r;
                    if (row < n) {
                        y1[row * COUT + c] = f2bf(acc[r]);   // b1 cancels in BN
                        st[i] += acc[r]; sq[i] += acc[r] * acc[r];
                    }
                }
            }
        }
    }
#pragma unroll
    for (int i = 0; i < 2; ++i) {
        st[i] += __shfl_xor(st[i], 16); st[i] += __shfl_xor(st[i], 32);
        sq[i] += __shfl_xor(sq[i], 16); sq[i] += __shfl_xor(sq[i], 32);
    }
    if (q == 0) {
#pragma unroll
        for (int i = 0; i < 2; ++i) {
            int c = (2 * wave + i) * 16 + lr;
            atomicAdd(&sumP[c * SPAD], st[i]);
            atomicAdd(&sqP[c * SPAD], sq[i]);
        }
    }
}

__global__ __launch_bounds__(256) void k_ag1(const int* __restrict__ flag,
        const u16* __restrict__ y0p, const int* __restrict__ rs,
        const int* __restrict__ csr, const void* Wr, const void* Wn,
        u16* y1_bf /*=d_out*/, u16* y1_ws,
        float* __restrict__ sumP, float* __restrict__ sqP, int n, int nch) {
    __shared__ u16 lds[64 * 130];
    u16* y1 = *flag ? y1_bf : y1_ws;
    if (*flag) ag1_impl<true >(y0p, rs, csr, Wr, Wn, y1, sumP, sqP, n, nch, lds);
    else       ag1_impl<false>(y0p, rs, csr, Wr, Wn, y1, sumP, sqP, n, nch, lds);
}

// ---------------- BN finalize (reads line-padded stats) ----------------
__global__ void k_bnfin(const int* __restrict__ flag,
                        const float* __restrict__ sumP, const float* __restrict__ sqP,
                        const void* g, const void* be,
                        float* __restrict__ scale, float* __restrict__ shift, int n) {
    int c = threadIdx.x;
    bool bf = (*flag != 0);
    float inv = 1.f / (float)n;
    float mu = sumP[c * SPAD] * inv;
    float var = fmaxf(sqP[c * SPAD] * inv - mu * mu, 0.f);
    float gv = bf ? bf2f(((const u16*)g)[c]) : ((const float*)g)[c];
    float bv = bf ? bf2f(((const u16*)be)[c]) : ((const float*)be)[c];
    float sc = gv * rsqrtf(var + BN_EPS);
    scale[c] = sc;
    shift[c] = bv - mu * sc;
}

// -------- final: out = relu(bn1(y1) + xb@Wlin^T + blin) -------------------
template<bool BF>
__device__ __forceinline__ void final_impl(const u16* xb, const u16* y1,
                                           const void* Wlin, const void* blin,
                                           const float* sc, const float* sh,
                                           void* out, int n, int nch, u16* lds) {
    const int ST = 130;
    int tid = threadIdx.x;
    int wave = tid >> 6, lane = tid & 63, lr = lane & 15, q = lane >> 4;

    short8 wf[2][2];
    float blc[2], scc[2], shc[2];
#pragma unroll
    for (int i = 0; i < 2; ++i) {
        int c = (2 * wave + i) * 16 + lr;
#pragma unroll
        for (int ks = 0; ks < 2; ++ks)
            wf[i][ks] = ld8<BF>(Wlin, (long)c * CIN + ks * 32 + q * 8);
        blc[i] = ldf<BF>(blin, c);
        scc[i] = sc[c]; shc[i] = sh[c];
    }

    const int rowy = tid >> 4, wy = tid & 15;
    short8 ry[4];

    auto regload = [&](long chunk0) {
#pragma unroll
        for (int i = 0; i < 4; ++i) {
            long rg = chunk0 + rowy + i * 16; if (rg > n - 1) rg = n - 1;
            ry[i] = *(const short8*)(y1 + rg * COUT + wy * 8);
        }
    };

    int ch = blockIdx.x;
    if (ch < nch) regload((long)ch * 64);
    for (; ch < nch; ch += gridDim.x) {
        long chunk0 = (long)ch * 64;
        __syncthreads();
#pragma unroll
        for (int i = 0; i < 4; ++i)
            *(short8*)(lds + (rowy + i * 16) * ST + wy * 8) = ry[i];
        __syncthreads();
        long nxt = (long)ch + gridDim.x;
        if (nxt < nch) regload(nxt * 64);

#pragma unroll
        for (int t = 0; t < 4; ++t) {
            long rg = chunk0 + t * 16 + lr; if (rg > n - 1) rg = n - 1;
            short8 a[2];
#pragma unroll
            for (int ks = 0; ks < 2; ++ks)
                a[ks] = *(const short8*)(xb + rg * CIN + ks * 32 + q * 8);
#pragma unroll
            for (int i = 0; i < 2; ++i) {
                f32x4 acc = {0.f, 0.f, 0.f, 0.f};
                acc = __builtin_amdgcn_mfma_f32_16x16x32_bf16(a[0], wf[i][0], acc, 0, 0, 0);
                acc = __builtin_amdgcn_mfma_f32_16x16x32_bf16(a[1], wf[i][1], acc, 0, 0, 0);
                int c = (2 * wave + i) * 16 + lr;
#pragma unroll
                for (int r = 0; r < 4; ++r) {
                    long row = chunk0 + t * 16 + q * 4 + r;
                    if (row < n) {
                        float yv = bf2f(lds[(t * 16 + q * 4 + r) * ST + c]);
                        float v = acc[r] + blc[i] + yv * scc[i] + shc[i];
                        v = fmaxf(v, 0.f);
                        if (BF) ((u16*)out)[row * COUT + c] = f2bf(v);
                        else    ((float*)out)[row * COUT + c] = v;
                    }
                }
            }
        }
    }
}

__global__ __launch_bounds__(256) void k_final(const int* __restrict__ flag,
        const u16* __restrict__ xb, const void* Wlin, const void* blin,
        const u16* y1_bf /*=d_out*/, const u16* y1_ws,
        const float* __restrict__ sc, const float* __restrict__ sh,
        void* out, int n, int nch) {
    __shared__ u16 lds[64 * 130];
    const u16* y1 = *flag ? y1_bf : y1_ws;
    if (*flag) final_impl<true >(xb, y1, Wlin, blin, sc, sh, out, n, nch, lds);
    else       final_impl<false>(xb, y1, Wlin, blin, sc, sh, out, n, nch, lds);
}

extern "C" void kernel_launch(void* const* d_in, const int* in_sizes, int n_in,
                              void* d_out, int out_size, void* d_ws, size_t ws_size,
                              hipStream_t stream) {
    (void)n_in; (void)out_size; (void)ws_size;
    const void* x    = d_in[0];
    const int*  ei   = (const int*)d_in[1];
    const void* Wr0  = d_in[2];
    const void* Wn0  = d_in[3];
    /* b0 dropped: BN-invariant */
    const void* g0   = d_in[5];
    const void* be0  = d_in[6];
    const void* Wr1  = d_in[7];
    const void* Wn1  = d_in[8];
    /* b1 dropped */
    const void* g1   = d_in[10];
    const void* be1  = d_in[11];
    const void* Wlin = d_in[12];
    const void* blin = d_in[13];

    const int N = in_sizes[0] / CIN;
    const int E = in_sizes[1] / 2;
    const int* src = ei;
    const int* dst = ei + E;
    const int NP = (N + PNODES - 1) >> PSH;   // <= MAXP for N <= 131072

    // ---- workspace carve (256B aligned) ----
    char* base = (char*)d_ws;
    size_t off = 0;
    auto carve = [&](size_t bytes) -> void* {
        void* p = base + off;
        off = (off + bytes + 255) & ~(size_t)255;
        return p;
    };
    int*   flag      = (int*)carve(256);
    int*   pcount    = (int*)carve(MAXP * PCPAD * sizeof(int));
    int*   pstart    = (int*)carve((MAXP + 1) * sizeof(int));
    int*   pcursor   = (int*)carve(MAXP * CURPAD * sizeof(int));
    float* statsP    = (float*)carve(4 * 128 * SPAD * sizeof(float));
    float* scsh      = (float*)carve(512 * sizeof(float));
    int*   row_start = (int*)carve((size_t)(N + 1) * sizeof(int));
    unsigned int* barr = (unsigned int*)carve((size_t)E * sizeof(int));
    int*   csr       = (int*)carve((size_t)E * sizeof(int));
    u16*   xb        = (u16*)carve((size_t)N * CIN * sizeof(u16));
    u16*   aggu      = (u16*)carve((size_t)N * COUT * sizeof(u16));
    u16*   y0        = (u16*)carve((size_t)N * COUT * sizeof(u16));
    u16*   y1_ws     = (u16*)carve((size_t)N * COUT * sizeof(u16));

    float* sum0P = statsP;
    float* sq0P  = statsP + 128 * SPAD;
    float* sum1P = statsP + 256 * SPAD;
    float* sq1P  = statsP + 384 * SPAD;

    hipMemsetAsync(pcount, 0, MAXP * PCPAD * sizeof(int), stream);
    hipMemsetAsync(statsP, 0, 4 * 128 * SPAD * sizeof(float), stream);

    const int nwb = (N + 3) / 4;        // wave-per-node agg blocks
    const int nch = (N + 63) / 64;      // 64-row chunks
    const int ntl = (E + 4095) / 4096;  // pfill tiles
    const int G   = nch < 1024 ? nch : 1024;  // persistent grid
    const long nq = (long)N * 16;       // y0 uint4-quads
    const long n8 = (long)N * CIN / 8;  // xb 8-elem groups
    int g2 = (int)((nq + 255) / 256); if (g2 > 2048) g2 = 2048;
    int g3 = (int)((n8 + 255) / 256); if (g3 > 1024) g3 = 1024;

    k_prep<<<257, 256, 0, stream>>>((const unsigned int*)x, flag, dst, pcount, E, NP);
    k_pscan<<<1, MAXP, 0, stream>>>(pcount, pstart, pcursor, NP, E);
    k_fill2<<<ntl + g3, 256, 0, stream>>>(src, dst, pcursor, barr, E, NP, ntl,
                                          flag, x, xb, n8);
    k_psort<<<NP, 256, 0, stream>>>(barr, pstart, csr, row_start, N, NP, E);

    k_agg0 <<<nwb, 256, 0, stream>>>(xb, row_start, csr, aggu, N);
    k_gemm0<<<G, 256, 0, stream>>>(flag, xb, aggu, Wr0, Wn0, y0,
                                   sum0P, sq0P, N, nch);
    k_bnfin<<<1, 128, 0, stream>>>(flag, sum0P, sq0P, g0, be0,
                                   scsh, scsh + 128, N);

    k_y0p<<<g2, 256, 0, stream>>>((unsigned int*)y0, scsh, scsh + 128, nq);

    k_ag1<<<G, 256, 0, stream>>>(flag, y0, row_start, csr, Wr1, Wn1,
                                 (u16*)d_out, y1_ws, sum1P, sq1P, N, nch);
    k_bnfin<<<1, 128, 0, stream>>>(flag, sum1P, sq1P, g1, be1,
                                   scsh + 256, scsh + 384, N);

    k_final<<<G, 256, 0, stream>>>(flag, xb, Wlin, blin,
                                   (const u16*)d_out, y1_ws,
                                   scsh + 256, scsh + 384, d_out, N, nch);
}

// Round 12
// 376.775 us; speedup vs baseline: 1.0998x; 1.0998x over previous
//
#include <hip/hip_runtime.h>
#include <stdint.h>

// ResBlock: GraphConv(64->128) -> BN -> ReLU -> GraphConv(128->128) -> BN
//           + (x @ Wlin^T + blin) residual -> ReLU.
// Runtime dtype probe (bf16 vs f32).
// R20: revert R19's agg1+gemm1 fusion (151.5us: barrier-phased fusion cut
// gather TLP 28->8 waves/CU, tripling gather time). Back to R18 (385us best)
// + one measured-good swap: gemm1 restored to the R10/R14 LDS-staged form
// with register prefetch (measured ~59.5us vs direct-global's 63.5us).
// R18 base: xb bf16 materialization, direct-global gemm0, persistent
// G=1024 grids, prep/fill2 fusions, PSH=8, register BN stats + line-padded
// atomics, y0p pass, 4-deep agg batches.

#define CIN 64
#define COUT 128
#define BN_EPS 1e-5f
#define CURPAD 32              // ints: one 128B line per cursor
#define PCPAD 32               // ints: one 128B line per pcount entry
#define SPAD 32                // floats: one 128B line per stats channel
#define PSH 8                  // partition = dst >> PSH  (256 nodes)
#define PNODES (1 << PSH)
#define MAXP 512               // supports N <= 131072

typedef unsigned short u16;
typedef short short8 __attribute__((ext_vector_type(8)));
typedef float f32x4 __attribute__((ext_vector_type(4)));

__device__ __forceinline__ float bf2f(u16 u) {
    union { unsigned int i; float f; } v; v.i = ((unsigned int)u) << 16; return v.f;
}
__device__ __forceinline__ u16 f2bf(float f) {
    union { float f; unsigned int i; } v; v.f = f;
    unsigned int r = v.i + 0x7fffu + ((v.i >> 16) & 1u);  // RNE; finite inputs
    return (u16)(r >> 16);
}
__device__ __forceinline__ float lo16(unsigned int w) { return bf2f((u16)(w & 0xffffu)); }
__device__ __forceinline__ float hi16(unsigned int w) { return bf2f((u16)(w >> 16)); }

template<bool BF> __device__ __forceinline__ float ldf(const void* p, long i) {
    if (BF) return bf2f(((const u16*)p)[i]);
    return ((const float*)p)[i];
}
template<bool BF> __device__ __forceinline__ short8 ld8(const void* p, long i) {
    if (BF) return *(const short8*)((const u16*)p + i);
    const float* f = (const float*)p + i;
    short8 r;
#pragma unroll
    for (int j = 0; j < 8; ++j) r[j] = (short)f2bf(f[j]);
    return r;
}

__device__ __forceinline__ void acc8(float* a, uint4 w) {
    a[0] += lo16(w.x); a[1] += hi16(w.x);
    a[2] += lo16(w.y); a[3] += hi16(w.y);
    a[4] += lo16(w.z); a[5] += hi16(w.z);
    a[6] += lo16(w.w); a[7] += hi16(w.w);
}

// ---- K1: fused dtype-detect (block 0) + partition histogram (rest) ------
__global__ __launch_bounds__(256) void k_prep(const unsigned int* __restrict__ x,
        int* __restrict__ flag, const int* __restrict__ dst,
        int* __restrict__ pcount, int E, int np) {
    if (blockIdx.x == 0) {
        if (threadIdx.x < 64) {
            int lane = threadIdx.x;
            int cnt = 0;
#pragma unroll
            for (int i = 0; i < 8; ++i) {
                unsigned int w = x[lane * 8 + i];
                unsigned int e0 = (w >> 7) & 0xFFu, e1 = (w >> 23) & 0xFFu;
                cnt += (e0 >= 0x60u && e0 <= 0x8Eu);
                cnt += (e1 >= 0x60u && e1 <= 0x8Eu);
            }
            for (int o = 32; o; o >>= 1) cnt += __shfl_down(cnt, o);
            if (lane == 0) *flag = (cnt > 850) ? 1 : 0;   // 1 => bf16
        }
        return;
    }
    __shared__ int h[MAXP];
    int bid = blockIdx.x - 1;
    int nb = gridDim.x - 1;
    for (int i = threadIdx.x; i < np; i += 256) h[i] = 0;
    __syncthreads();
    int stride = nb * 256;
    for (int e = bid * 256 + threadIdx.x; e < E; e += stride)
        atomicAdd(&h[dst[e] >> PSH], 1);
    __syncthreads();
    for (int i = threadIdx.x; i < np; i += 256)
        if (h[i]) atomicAdd(&pcount[i * PCPAD], h[i]);
}

__global__ void k_pscan(const int* __restrict__ pcount, int* __restrict__ pstart,
                        int* __restrict__ pcursor, int np, int E) {
    __shared__ int s[MAXP];
    int t = threadIdx.x;  // MAXP threads
    int v = (t < np) ? pcount[t * PCPAD] : 0;
    s[t] = v; __syncthreads();
    for (int o = 1; o < MAXP; o <<= 1) {
        int u = (t >= o) ? s[t - o] : 0;
        __syncthreads(); s[t] += u; __syncthreads();
    }
    if (t < np) {
        int ex = s[t] - v;
        pstart[t] = ex;
        pcursor[t * CURPAD] = ex;
    }
    if (t == 0) pstart[np] = E;
}

// ---- K3: fused pfill (blocks < ntl) + xbf stream (blocks >= ntl) --------
__global__ __launch_bounds__(256) void k_fill2(const int* __restrict__ src,
        const int* __restrict__ dst, int* __restrict__ pcursor,
        unsigned int* __restrict__ barr, int E, int np, int ntl,
        const int* __restrict__ flag, const void* __restrict__ x,
        u16* __restrict__ xb, long n8) {
    __shared__ int cnt[MAXP], gb[MAXP], loc[MAXP];
    int tid = threadIdx.x;
    if (blockIdx.x >= ntl) {
        // ---- xbf part: xb = bf16(x) ----
        int nb = gridDim.x - ntl;
        long idx = (long)(blockIdx.x - ntl) * 256 + tid;
        long stride = (long)nb * 256;
        uint4* d4 = (uint4*)xb;
        if (*flag) {
            const uint4* s4 = (const uint4*)x;
            for (; idx < n8; idx += stride) d4[idx] = s4[idx];
        } else {
            const float4* s4 = (const float4*)x;
            for (; idx < n8; idx += stride) {
                float4 a = s4[idx * 2], b = s4[idx * 2 + 1];
                uint4 o;
                o.x = (unsigned int)f2bf(a.x) | ((unsigned int)f2bf(a.y) << 16);
                o.y = (unsigned int)f2bf(a.z) | ((unsigned int)f2bf(a.w) << 16);
                o.z = (unsigned int)f2bf(b.x) | ((unsigned int)f2bf(b.y) << 16);
                o.w = (unsigned int)f2bf(b.z) | ((unsigned int)f2bf(b.w) << 16);
                d4[idx] = o;
            }
        }
        return;
    }
    // ---- pfill part: rec = (dst & (PNODES-1)) << 20 | src ----
    int base = blockIdx.x * 4096;
    for (int i = tid; i < np; i += 256) { cnt[i] = 0; loc[i] = 0; }
    __syncthreads();
    int pk[16]; unsigned int rec[16];
#pragma unroll
    for (int k = 0; k < 16; ++k) {
        int e = base + k * 256 + tid;
        if (e < E) {
            int d = dst[e];
            pk[k] = d >> PSH;
            rec[k] = ((unsigned int)(d & (PNODES - 1)) << 20) | (unsigned int)src[e];
            atomicAdd(&cnt[pk[k]], 1);
        } else pk[k] = -1;
    }
    __syncthreads();
    for (int i = tid; i < np; i += 256)
        if (cnt[i]) gb[i] = atomicAdd(&pcursor[i * CURPAD], cnt[i]);
    __syncthreads();
#pragma unroll
    for (int k = 0; k < 16; ++k) {
        if (pk[k] >= 0) {
            int off = atomicAdd(&loc[pk[k]], 1);
            barr[gb[pk[k]] + off] = rec[k];
        }
    }
}

// Block per partition (PNODES=256): LDS counting sort -> csr + row_start.
__global__ __launch_bounds__(256) void k_psort(const unsigned int* __restrict__ barr,
        const int* __restrict__ pstart, int* __restrict__ csr,
        int* __restrict__ row_start, int n, int np, int E) {
    __shared__ int hist[PNODES], curs[PNODES], tsum[256];
    int tid = threadIdx.x;
    int p = blockIdx.x;
    int e0 = pstart[p], e1 = pstart[p + 1];
    int node0 = p << PSH;
    hist[tid] = 0;
    __syncthreads();
    for (int t = e0 + tid; t < e1; t += 256)
        atomicAdd(&hist[barr[t] >> 20], 1);
    __syncthreads();
    int v = hist[tid];
    tsum[tid] = v; __syncthreads();
    for (int o = 1; o < 256; o <<= 1) {
        int u = (tid >= o) ? tsum[tid - o] : 0;
        __syncthreads(); tsum[tid] += u; __syncthreads();
    }
    int ex = tsum[tid] - v;
    curs[tid] = ex;
    int nd = node0 + tid;
    if (nd < n) row_start[nd] = e0 + ex;
    if (p == np - 1 && tid == 0) row_start[n] = E;
    __syncthreads();
    for (int t = e0 + tid; t < e1; t += 256) {
        unsigned int rec = barr[t];
        int pos = atomicAdd(&curs[rec >> 20], 1);
        csr[e0 + pos] = (int)(rec & 0xFFFFF);
    }
}

// ---- aggregation 0: bf16 gather on xb rows (128B), 4-deep batches -------
__global__ __launch_bounds__(256) void k_agg0(const u16* __restrict__ xb,
        const int* __restrict__ rs, const int* __restrict__ csr,
        u16* __restrict__ agg, int n) {
    int i = blockIdx.x * 4 + (threadIdx.x >> 6);
    if (i >= n) return;
    int lane = threadIdx.x & 63;
    int slot = lane >> 4, cp = lane & 15;   // xb row = 128B = 16 x uint2
    const unsigned int* x32 = (const unsigned int*)xb;
    int b = rs[i], e = rs[i + 1];
    float acc[4] = {0.f, 0.f, 0.f, 0.f};
    int t = b + slot;
    for (; t + 12 < e; t += 16) {
        int j0 = csr[t], j1 = csr[t + 4], j2 = csr[t + 8], j3 = csr[t + 12];
        uint2 w0 = *((const uint2*)(x32 + (long)j0 * 32) + cp);
        uint2 w1 = *((const uint2*)(x32 + (long)j1 * 32) + cp);
        uint2 w2 = *((const uint2*)(x32 + (long)j2 * 32) + cp);
        uint2 w3 = *((const uint2*)(x32 + (long)j3 * 32) + cp);
        acc[0] += lo16(w0.x) + lo16(w1.x); acc[1] += hi16(w0.x) + hi16(w1.x);
        acc[2] += lo16(w0.y) + lo16(w1.y); acc[3] += hi16(w0.y) + hi16(w1.y);
        acc[0] += lo16(w2.x) + lo16(w3.x); acc[1] += hi16(w2.x) + hi16(w3.x);
        acc[2] += lo16(w2.y) + lo16(w3.y); acc[3] += hi16(w2.y) + hi16(w3.y);
    }
    for (; t < e; t += 4) {
        int j0 = csr[t];
        uint2 w0 = *((const uint2*)(x32 + (long)j0 * 32) + cp);
        acc[0] += lo16(w0.x); acc[1] += hi16(w0.x);
        acc[2] += lo16(w0.y); acc[3] += hi16(w0.y);
    }
#pragma unroll
    for (int k = 0; k < 4; ++k) {
        acc[k] += __shfl_xor(acc[k], 16);
        acc[k] += __shfl_xor(acc[k], 32);
    }
    if (slot == 0) {
        uint2 o;
        o.x = (unsigned int)f2bf(acc[0]) | ((unsigned int)f2bf(acc[1]) << 16);
        o.y = (unsigned int)f2bf(acc[2]) | ((unsigned int)f2bf(acc[3]) << 16);
        *((uint2*)((unsigned int*)agg + (long)i * 32) + cp) = o;
    }
}

// ---- y0p = relu(bn0(y0)) materialized IN-PLACE (bf16), streaming --------
__global__ __launch_bounds__(256) void k_y0p(unsigned int* __restrict__ y0,
        const float* __restrict__ sc, const float* __restrict__ sh, long nq) {
    long idx = (long)blockIdx.x * 256 + threadIdx.x;
    int colq = threadIdx.x & 15;
    float s8[8], h8[8];
#pragma unroll
    for (int j = 0; j < 8; ++j) { s8[j] = sc[colq * 8 + j]; h8[j] = sh[colq * 8 + j]; }
    long stride = (long)gridDim.x * 256;
    uint4* p = (uint4*)y0;
    for (; idx < nq; idx += stride) {
        uint4 w = p[idx];
        unsigned int r[4] = {w.x, w.y, w.z, w.w};
        uint4 o;
        unsigned int* po = (unsigned int*)&o;
#pragma unroll
        for (int d = 0; d < 4; ++d) {
            float a = fmaxf(lo16(r[d]) * s8[2 * d]     + h8[2 * d],     0.f);
            float b = fmaxf(hi16(r[d]) * s8[2 * d + 1] + h8[2 * d + 1], 0.f);
            po[d] = (unsigned int)f2bf(a) | ((unsigned int)f2bf(b) << 16);
        }
        p[idx] = o;
    }
}

// ------- aggregation 1: pure bf16 gather, 4-deep batches -----------------
__global__ __launch_bounds__(256) void k_agg1(const u16* __restrict__ y0p,
        const int* __restrict__ rs, const int* __restrict__ csr,
        u16* __restrict__ agg, int n) {
    int i = blockIdx.x * 4 + (threadIdx.x >> 6);
    if (i >= n) return;
    int lane = threadIdx.x & 63;
    int slot = lane >> 4, cp = lane & 15;   // y0p row = 256B = 16 x uint4
    const unsigned int* y32 = (const unsigned int*)y0p;
    int b = rs[i], e = rs[i + 1];
    float acc[8] = {0.f, 0.f, 0.f, 0.f, 0.f, 0.f, 0.f, 0.f};
    int t = b + slot;
    for (; t + 12 < e; t += 16) {
        int j0 = csr[t], j1 = csr[t + 4], j2 = csr[t + 8], j3 = csr[t + 12];
        uint4 w0 = *((const uint4*)(y32 + (long)j0 * 64) + cp);
        uint4 w1 = *((const uint4*)(y32 + (long)j1 * 64) + cp);
        uint4 w2 = *((const uint4*)(y32 + (long)j2 * 64) + cp);
        uint4 w3 = *((const uint4*)(y32 + (long)j3 * 64) + cp);
        acc8(acc, w0); acc8(acc, w1); acc8(acc, w2); acc8(acc, w3);
    }
    for (; t < e; t += 4) {
        int j0 = csr[t];
        uint4 w0 = *((const uint4*)(y32 + (long)j0 * 64) + cp);
        acc8(acc, w0);
    }
#pragma unroll
    for (int k = 0; k < 8; ++k) {
        acc[k] += __shfl_xor(acc[k], 16);
        acc[k] += __shfl_xor(acc[k], 32);
    }
    if (slot == 0) {
        uint4 o;
        o.x = (unsigned int)f2bf(acc[0]) | ((unsigned int)f2bf(acc[1]) << 16);
        o.y = (unsigned int)f2bf(acc[2]) | ((unsigned int)f2bf(acc[3]) << 16);
        o.z = (unsigned int)f2bf(acc[4]) | ((unsigned int)f2bf(acc[5]) << 16);
        o.w = (unsigned int)f2bf(acc[6]) | ((unsigned int)f2bf(acc[7]) << 16);
        *((uint4*)((unsigned int*)agg + (long)i * 64) + cp) = o;
    }
}

// ------ GEMM0 (direct-global, persistent): y0 = [xb|agg0] @ W0^T ----------
template<bool BF>
__device__ __forceinline__ void gemm0_impl(const u16* xb, const u16* agg,
                                           const void* Wr, const void* Wn,
                                           u16* y0, float* sumP, float* sqP,
                                           int n, int nch) {
    int tid = threadIdx.x;
    int wave = tid >> 6, lane = tid & 63, lr = lane & 15, q = lane >> 4;

    short8 wf[2][4];
#pragma unroll
    for (int i = 0; i < 2; ++i) {
        int c = (2 * wave + i) * 16 + lr;
#pragma unroll
        for (int ks = 0; ks < 4; ++ks) {
            const void* W = (ks < 2) ? Wr : Wn;
            wf[i][ks] = ld8<BF>(W, (long)c * CIN + (ks & 1) * 32 + q * 8);
        }
    }

    float st[2] = {0.f, 0.f}, sq[2] = {0.f, 0.f};
    for (int ch = blockIdx.x; ch < nch; ch += gridDim.x) {
        long chunk0 = (long)ch * 64;
#pragma unroll
        for (int t = 0; t < 4; ++t) {
            long rg = chunk0 + t * 16 + lr; if (rg > n - 1) rg = n - 1;
            short8 a[4];
#pragma unroll
            for (int ks = 0; ks < 2; ++ks)
                a[ks] = *(const short8*)(xb + rg * CIN + ks * 32 + q * 8);
#pragma unroll
            for (int ks = 0; ks < 2; ++ks)
                a[2 + ks] = *(const short8*)(agg + rg * CIN + ks * 32 + q * 8);
#pragma unroll
            for (int i = 0; i < 2; ++i) {
                f32x4 acc = {0.f, 0.f, 0.f, 0.f};
#pragma unroll
                for (int ks = 0; ks < 4; ++ks)
                    acc = __builtin_amdgcn_mfma_f32_16x16x32_bf16(a[ks], wf[i][ks], acc, 0, 0, 0);
                int c = (2 * wave + i) * 16 + lr;
#pragma unroll
                for (int r = 0; r < 4; ++r) {
                    long row = chunk0 + t * 16 + q * 4 + r;
                    if (row < n) {
                        y0[row * COUT + c] = f2bf(acc[r]);   // b0 cancels in BN
                        st[i] += acc[r]; sq[i] += acc[r] * acc[r];
                    }
                }
            }
        }
    }
#pragma unroll
    for (int i = 0; i < 2; ++i) {
        st[i] += __shfl_xor(st[i], 16); st[i] += __shfl_xor(st[i], 32);
        sq[i] += __shfl_xor(sq[i], 16); sq[i] += __shfl_xor(sq[i], 32);
    }
    if (q == 0) {
#pragma unroll
        for (int i = 0; i < 2; ++i) {
            int c = (2 * wave + i) * 16 + lr;
            atomicAdd(&sumP[c * SPAD], st[i]);
            atomicAdd(&sqP[c * SPAD], sq[i]);
        }
    }
}

__global__ __launch_bounds__(256) void k_gemm0(const int* __restrict__ flag,
        const u16* __restrict__ xb, const u16* __restrict__ agg,
        const void* Wr, const void* Wn,
        u16* __restrict__ y0, float* __restrict__ sumP, float* __restrict__ sqP,
        int n, int nch) {
    if (*flag) gemm0_impl<true >(xb, agg, Wr, Wn, y0, sumP, sqP, n, nch);
    else       gemm0_impl<false>(xb, agg, Wr, Wn, y0, sumP, sqP, n, nch);
}

// ------ GEMM1 (LDS-staged + reg-prefetch, R10/R14 form): ------------------
// y1 = [y0p|agg1] @ [Wr1;Wn1]^T, fused stats. Measured ~59.5us vs 63.5
// direct-global.
template<bool BF>
__device__ __forceinline__ void gemm1_impl(const u16* y0p, const u16* agg,
                                           const void* Wr, const void* Wn,
                                           u16* y1, float* sumP, float* sqP,
                                           int n, int nch, u16* lds) {
    const int ST = 258;
    int tid = threadIdx.x;
    int wave = tid >> 6, lane = tid & 63, lr = lane & 15, q = lane >> 4;

    short8 wf[2][8];
#pragma unroll
    for (int i = 0; i < 2; ++i) {
        int c = (2 * wave + i) * 16 + lr;
#pragma unroll
        for (int ks = 0; ks < 8; ++ks) {
            const void* W = (ks < 4) ? Wr : Wn;
            wf[i][ks] = ld8<BF>(W, (long)c * COUT + (ks & 3) * 32 + q * 8);
        }
    }

    const int rowy = tid >> 4, wy = tid & 15;   // 128-wide rows: 4/thread
    short8 ry[4], rag[4];
    auto regload = [&](long chunk0) {
#pragma unroll
        for (int i = 0; i < 4; ++i) {
            long rg = chunk0 + rowy + i * 16; if (rg > n - 1) rg = n - 1;
            ry[i]  = *(const short8*)(y0p + rg * COUT + wy * 8);
            rag[i] = *(const short8*)(agg + rg * COUT + wy * 8);
        }
    };

    float st[2] = {0.f, 0.f}, sq[2] = {0.f, 0.f};
    int ch = blockIdx.x;
    if (ch < nch) regload((long)ch * 64);
    for (; ch < nch; ch += gridDim.x) {
        long chunk0 = (long)ch * 64;
        __syncthreads();
#pragma unroll
        for (int i = 0; i < 4; ++i) {
            *(short8*)(lds + (rowy + i * 16) * ST + wy * 8) = ry[i];
            *(short8*)(lds + (rowy + i * 16) * ST + 128 + wy * 8) = rag[i];
        }
        __syncthreads();
        long nxt = (long)ch + gridDim.x;
        if (nxt < nch) regload(nxt * 64);      // T14: prefetch next chunk

#pragma unroll
        for (int t = 0; t < 4; ++t) {
            short8 a[8];
#pragma unroll
            for (int ks = 0; ks < 8; ++ks)
                a[ks] = *(const short8*)(lds + (t * 16 + lr) * ST + ks * 32 + q * 8);
#pragma unroll
            for (int i = 0; i < 2; ++i) {
                f32x4 acc = {0.f, 0.f, 0.f, 0.f};
#pragma unroll
                for (int ks = 0; ks < 8; ++ks)
                    acc = __builtin_amdgcn_mfma_f32_16x16x32_bf16(a[ks], wf[i][ks], acc, 0, 0, 0);
                int c = (2 * wave + i) * 16 + lr;
#pragma unroll
                for (int r = 0; r < 4; ++r) {
                    long row = chunk0 + t * 16 + q * 4 + r;
                    if (row < n) {
                        y1[row * COUT + c] = f2bf(acc[r]);   // b1 cancels in BN
                        st[i] += acc[r]; sq[i] += acc[r] * acc[r];
                    }
                }
            }
        }
    }
#pragma unroll
    for (int i = 0; i < 2; ++i) {
        st[i] += __shfl_xor(st[i], 16); st[i] += __shfl_xor(st[i], 32);
        sq[i] += __shfl_xor(sq[i], 16); sq[i] += __shfl_xor(sq[i], 32);
    }
    if (q == 0) {
#pragma unroll
        for (int i = 0; i < 2; ++i) {
            int c = (2 * wave + i) * 16 + lr;
            atomicAdd(&sumP[c * SPAD], st[i]);
            atomicAdd(&sqP[c * SPAD], sq[i]);
        }
    }
}

__global__ __launch_bounds__(256) void k_gemm1(const int* __restrict__ flag,
        const u16* __restrict__ y0p, const u16* __restrict__ agg,
        const void* Wr, const void* Wn,
        u16* y1_bf /*=d_out*/, u16* y1_ws,
        float* __restrict__ sumP, float* __restrict__ sqP, int n, int nch) {
    __shared__ u16 lds[64 * 258];
    u16* y1 = *flag ? y1_bf : y1_ws;
    if (*flag) gemm1_impl<true >(y0p, agg, Wr, Wn, y1, sumP, sqP, n, nch, lds);
    else       gemm1_impl<false>(y0p, agg, Wr, Wn, y1, sumP, sqP, n, nch, lds);
}

// ---------------- BN finalize (reads line-padded stats) ----------------
__global__ void k_bnfin(const int* __restrict__ flag,
                        const float* __restrict__ sumP, const float* __restrict__ sqP,
                        const void* g, const void* be,
                        float* __restrict__ scale, float* __restrict__ shift, int n) {
    int c = threadIdx.x;
    bool bf = (*flag != 0);
    float inv = 1.f / (float)n;
    float mu = sumP[c * SPAD] * inv;
    float var = fmaxf(sqP[c * SPAD] * inv - mu * mu, 0.f);
    float gv = bf ? bf2f(((const u16*)g)[c]) : ((const float*)g)[c];
    float bv = bf ? bf2f(((const u16*)be)[c]) : ((const float*)be)[c];
    float sc = gv * rsqrtf(var + BN_EPS);
    scale[c] = sc;
    shift[c] = bv - mu * sc;
}

// -------- final: out = relu(bn1(y1) + xb@Wlin^T + blin) -------------------
template<bool BF>
__device__ __forceinline__ void final_impl(const u16* xb, const u16* y1,
                                           const void* Wlin, const void* blin,
                                           const float* sc, const float* sh,
                                           void* out, int n, int nch, u16* lds) {
    const int ST = 130;
    int tid = threadIdx.x;
    int wave = tid >> 6, lane = tid & 63, lr = lane & 15, q = lane >> 4;

    short8 wf[2][2];
    float blc[2], scc[2], shc[2];
#pragma unroll
    for (int i = 0; i < 2; ++i) {
        int c = (2 * wave + i) * 16 + lr;
#pragma unroll
        for (int ks = 0; ks < 2; ++ks)
            wf[i][ks] = ld8<BF>(Wlin, (long)c * CIN + ks * 32 + q * 8);
        blc[i] = ldf<BF>(blin, c);
        scc[i] = sc[c]; shc[i] = sh[c];
    }

    const int rowy = tid >> 4, wy = tid & 15;
    short8 ry[4];

    auto regload = [&](long chunk0) {
#pragma unroll
        for (int i = 0; i < 4; ++i) {
            long rg = chunk0 + rowy + i * 16; if (rg > n - 1) rg = n - 1;
            ry[i] = *(const short8*)(y1 + rg * COUT + wy * 8);
        }
    };

    int ch = blockIdx.x;
    if (ch < nch) regload((long)ch * 64);
    for (; ch < nch; ch += gridDim.x) {
        long chunk0 = (long)ch * 64;
        __syncthreads();
#pragma unroll
        for (int i = 0; i < 4; ++i)
            *(short8*)(lds + (rowy + i * 16) * ST + wy * 8) = ry[i];
        __syncthreads();
        long nxt = (long)ch + gridDim.x;
        if (nxt < nch) regload(nxt * 64);

#pragma unroll
        for (int t = 0; t < 4; ++t) {
            long rg = chunk0 + t * 16 + lr; if (rg > n - 1) rg = n - 1;
            short8 a[2];
#pragma unroll
            for (int ks = 0; ks < 2; ++ks)
                a[ks] = *(const short8*)(xb + rg * CIN + ks * 32 + q * 8);
#pragma unroll
            for (int i = 0; i < 2; ++i) {
                f32x4 acc = {0.f, 0.f, 0.f, 0.f};
                acc = __builtin_amdgcn_mfma_f32_16x16x32_bf16(a[0], wf[i][0], acc, 0, 0, 0);
                acc = __builtin_amdgcn_mfma_f32_16x16x32_bf16(a[1], wf[i][1], acc, 0, 0, 0);
                int c = (2 * wave + i) * 16 + lr;
#pragma unroll
                for (int r = 0; r < 4; ++r) {
                    long row = chunk0 + t * 16 + q * 4 + r;
                    if (row < n) {
                        float yv = bf2f(lds[(t * 16 + q * 4 + r) * ST + c]);
                        float v = acc[r] + blc[i] + yv * scc[i] + shc[i];
                        v = fmaxf(v, 0.f);
                        if (BF) ((u16*)out)[row * COUT + c] = f2bf(v);
                        else    ((float*)out)[row * COUT + c] = v;
                    }
                }
            }
        }
    }
}

__global__ __launch_bounds__(256) void k_final(const int* __restrict__ flag,
        const u16* __restrict__ xb, const void* Wlin, const void* blin,
        const u16* y1_bf /*=d_out*/, const u16* y1_ws,
        const float* __restrict__ sc, const float* __restrict__ sh,
        void* out, int n, int nch) {
    __shared__ u16 lds[64 * 130];
    const u16* y1 = *flag ? y1_bf : y1_ws;
    if (*flag) final_impl<true >(xb, y1, Wlin, blin, sc, sh, out, n, nch, lds);
    else       final_impl<false>(xb, y1, Wlin, blin, sc, sh, out, n, nch, lds);
}

extern "C" void kernel_launch(void* const* d_in, const int* in_sizes, int n_in,
                              void* d_out, int out_size, void* d_ws, size_t ws_size,
                              hipStream_t stream) {
    (void)n_in; (void)out_size; (void)ws_size;
    const void* x    = d_in[0];
    const int*  ei   = (const int*)d_in[1];
    const void* Wr0  = d_in[2];
    const void* Wn0  = d_in[3];
    /* b0 dropped: BN-invariant */
    const void* g0   = d_in[5];
    const void* be0  = d_in[6];
    const void* Wr1  = d_in[7];
    const void* Wn1  = d_in[8];
    /* b1 dropped */
    const void* g1   = d_in[10];
    const void* be1  = d_in[11];
    const void* Wlin = d_in[12];
    const void* blin = d_in[13];

    const int N = in_sizes[0] / CIN;
    const int E = in_sizes[1] / 2;
    const int* src = ei;
    const int* dst = ei + E;
    const int NP = (N + PNODES - 1) >> PSH;   // <= MAXP for N <= 131072

    // ---- workspace carve (256B aligned) ----
    char* base = (char*)d_ws;
    size_t off = 0;
    auto carve = [&](size_t bytes) -> void* {
        void* p = base + off;
        off = (off + bytes + 255) & ~(size_t)255;
        return p;
    };
    int*   flag      = (int*)carve(256);
    int*   pcount    = (int*)carve(MAXP * PCPAD * sizeof(int));
    int*   pstart    = (int*)carve((MAXP + 1) * sizeof(int));
    int*   pcursor   = (int*)carve(MAXP * CURPAD * sizeof(int));
    float* statsP    = (float*)carve(4 * 128 * SPAD * sizeof(float));
    float* scsh      = (float*)carve(512 * sizeof(float));
    int*   row_start = (int*)carve((size_t)(N + 1) * sizeof(int));
    unsigned int* barr = (unsigned int*)carve((size_t)E * sizeof(int));
    int*   csr       = (int*)carve((size_t)E * sizeof(int));
    u16*   xb        = (u16*)carve((size_t)N * CIN * sizeof(u16));
    u16*   aggu      = (u16*)carve((size_t)N * COUT * sizeof(u16));
    u16*   y0        = (u16*)carve((size_t)N * COUT * sizeof(u16));
    u16*   y1_ws     = (u16*)carve((size_t)N * COUT * sizeof(u16));

    float* sum0P = statsP;
    float* sq0P  = statsP + 128 * SPAD;
    float* sum1P = statsP + 256 * SPAD;
    float* sq1P  = statsP + 384 * SPAD;

    hipMemsetAsync(pcount, 0, MAXP * PCPAD * sizeof(int), stream);
    hipMemsetAsync(statsP, 0, 4 * 128 * SPAD * sizeof(float), stream);

    const int nwb = (N + 3) / 4;        // wave-per-node agg blocks
    const int nch = (N + 63) / 64;      // 64-row chunks
    const int ntl = (E + 4095) / 4096;  // pfill tiles
    const int G   = nch < 1024 ? nch : 1024;  // persistent grid
    const long nq = (long)N * 16;       // y0 uint4-quads
    const long n8 = (long)N * CIN / 8;  // xb 8-elem groups
    int g2 = (int)((nq + 255) / 256); if (g2 > 2048) g2 = 2048;
    int g3 = (int)((n8 + 255) / 256); if (g3 > 1024) g3 = 1024;

    k_prep<<<257, 256, 0, stream>>>((const unsigned int*)x, flag, dst, pcount, E, NP);
    k_pscan<<<1, MAXP, 0, stream>>>(pcount, pstart, pcursor, NP, E);
    k_fill2<<<ntl + g3, 256, 0, stream>>>(src, dst, pcursor, barr, E, NP, ntl,
                                          flag, x, xb, n8);
    k_psort<<<NP, 256, 0, stream>>>(barr, pstart, csr, row_start, N, NP, E);

    k_agg0 <<<nwb, 256, 0, stream>>>(xb, row_start, csr, aggu, N);
    k_gemm0<<<G, 256, 0, stream>>>(flag, xb, aggu, Wr0, Wn0, y0,
                                   sum0P, sq0P, N, nch);
    k_bnfin<<<1, 128, 0, stream>>>(flag, sum0P, sq0P, g0, be0,
                                   scsh, scsh + 128, N);

    k_y0p<<<g2, 256, 0, stream>>>((unsigned int*)y0, scsh, scsh + 128, nq);

    k_agg1 <<<nwb, 256, 0, stream>>>(y0, row_start, csr, aggu, N);
    k_gemm1<<<G, 256, 0, stream>>>(flag, y0, aggu, Wr1, Wn1,
                                   (u16*)d_out, y1_ws, sum1P, sq1P, N, nch);
    k_bnfin<<<1, 128, 0, stream>>>(flag, sum1P, sq1P, g1, be1,
                                   scsh + 256, scsh + 384, N);

    k_final<<<G, 256, 0, stream>>>(flag, xb, Wlin, blin,
                                   (const u16*)d_out, y1_ws,
                                   scsh + 256, scsh + 384, d_out, N, nch);
}

// Round 14
// 368.494 us; speedup vs baseline: 1.1245x; 1.0225x over previous
//
#include <hip/hip_runtime.h>
#include <stdint.h>

// ResBlock: GraphConv(64->128) -> BN -> ReLU -> GraphConv(128->128) -> BN
//           + (x @ Wlin^T + blin) residual -> ReLU.
// Runtime dtype probe (bf16 vs f32).
// R22 == R21 resubmit (bench infra failed twice; no counters returned --
// same failure mode as R11, which resolved on plain resubmission).
// R21: R20 (376.8us best) + ONE variable: G 1024->512 for the persistent
// dense kernels. R17 measured +5.2us for gemm1 going 1024->1563 blocks
// (per-block overhead); extrapolating down, 512 blocks (3 chunks each,
// 2x weight amortization) should recover a few us on each dense kernel.
// Pre-commit: if total >= 377, declare roofline next round.
// R20 base: xb bf16 materialization, direct-global gemm0, LDS-staged
// gemm1 w/ reg-prefetch, prep/fill2 fusions, PSH=8, register BN stats +
// line-padded atomics, y0p pass, 4-deep agg batches.

#define CIN 64
#define COUT 128
#define BN_EPS 1e-5f
#define CURPAD 32              // ints: one 128B line per cursor
#define PCPAD 32               // ints: one 128B line per pcount entry
#define SPAD 32                // floats: one 128B line per stats channel
#define PSH 8                  // partition = dst >> PSH  (256 nodes)
#define PNODES (1 << PSH)
#define MAXP 512               // supports N <= 131072

typedef unsigned short u16;
typedef short short8 __attribute__((ext_vector_type(8)));
typedef float f32x4 __attribute__((ext_vector_type(4)));

__device__ __forceinline__ float bf2f(u16 u) {
    union { unsigned int i; float f; } v; v.i = ((unsigned int)u) << 16; return v.f;
}
__device__ __forceinline__ u16 f2bf(float f) {
    union { float f; unsigned int i; } v; v.f = f;
    unsigned int r = v.i + 0x7fffu + ((v.i >> 16) & 1u);  // RNE; finite inputs
    return (u16)(r >> 16);
}
__device__ __forceinline__ float lo16(unsigned int w) { return bf2f((u16)(w & 0xffffu)); }
__device__ __forceinline__ float hi16(unsigned int w) { return bf2f((u16)(w >> 16)); }

template<bool BF> __device__ __forceinline__ float ldf(const void* p, long i) {
    if (BF) return bf2f(((const u16*)p)[i]);
    return ((const float*)p)[i];
}
template<bool BF> __device__ __forceinline__ short8 ld8(const void* p, long i) {
    if (BF) return *(const short8*)((const u16*)p + i);
    const float* f = (const float*)p + i;
    short8 r;
#pragma unroll
    for (int j = 0; j < 8; ++j) r[j] = (short)f2bf(f[j]);
    return r;
}

__device__ __forceinline__ void acc8(float* a, uint4 w) {
    a[0] += lo16(w.x); a[1] += hi16(w.x);
    a[2] += lo16(w.y); a[3] += hi16(w.y);
    a[4] += lo16(w.z); a[5] += hi16(w.z);
    a[6] += lo16(w.w); a[7] += hi16(w.w);
}

// ---- K1: fused dtype-detect (block 0) + partition histogram (rest) ------
__global__ __launch_bounds__(256) void k_prep(const unsigned int* __restrict__ x,
        int* __restrict__ flag, const int* __restrict__ dst,
        int* __restrict__ pcount, int E, int np) {
    if (blockIdx.x == 0) {
        if (threadIdx.x < 64) {
            int lane = threadIdx.x;
            int cnt = 0;
#pragma unroll
            for (int i = 0; i < 8; ++i) {
                unsigned int w = x[lane * 8 + i];
                unsigned int e0 = (w >> 7) & 0xFFu, e1 = (w >> 23) & 0xFFu;
                cnt += (e0 >= 0x60u && e0 <= 0x8Eu);
                cnt += (e1 >= 0x60u && e1 <= 0x8Eu);
            }
            for (int o = 32; o; o >>= 1) cnt += __shfl_down(cnt, o);
            if (lane == 0) *flag = (cnt > 850) ? 1 : 0;   // 1 => bf16
        }
        return;
    }
    __shared__ int h[MAXP];
    int bid = blockIdx.x - 1;
    int nb = gridDim.x - 1;
    for (int i = threadIdx.x; i < np; i += 256) h[i] = 0;
    __syncthreads();
    int stride = nb * 256;
    for (int e = bid * 256 + threadIdx.x; e < E; e += stride)
        atomicAdd(&h[dst[e] >> PSH], 1);
    __syncthreads();
    for (int i = threadIdx.x; i < np; i += 256)
        if (h[i]) atomicAdd(&pcount[i * PCPAD], h[i]);
}

__global__ void k_pscan(const int* __restrict__ pcount, int* __restrict__ pstart,
                        int* __restrict__ pcursor, int np, int E) {
    __shared__ int s[MAXP];
    int t = threadIdx.x;  // MAXP threads
    int v = (t < np) ? pcount[t * PCPAD] : 0;
    s[t] = v; __syncthreads();
    for (int o = 1; o < MAXP; o <<= 1) {
        int u = (t >= o) ? s[t - o] : 0;
        __syncthreads(); s[t] += u; __syncthreads();
    }
    if (t < np) {
        int ex = s[t] - v;
        pstart[t] = ex;
        pcursor[t * CURPAD] = ex;
    }
    if (t == 0) pstart[np] = E;
}

// ---- K3: fused pfill (blocks < ntl) + xbf stream (blocks >= ntl) --------
__global__ __launch_bounds__(256) void k_fill2(const int* __restrict__ src,
        const int* __restrict__ dst, int* __restrict__ pcursor,
        unsigned int* __restrict__ barr, int E, int np, int ntl,
        const int* __restrict__ flag, const void* __restrict__ x,
        u16* __restrict__ xb, long n8) {
    __shared__ int cnt[MAXP], gb[MAXP], loc[MAXP];
    int tid = threadIdx.x;
    if (blockIdx.x >= ntl) {
        // ---- xbf part: xb = bf16(x) ----
        int nb = gridDim.x - ntl;
        long idx = (long)(blockIdx.x - ntl) * 256 + tid;
        long stride = (long)nb * 256;
        uint4* d4 = (uint4*)xb;
        if (*flag) {
            const uint4* s4 = (const uint4*)x;
            for (; idx < n8; idx += stride) d4[idx] = s4[idx];
        } else {
            const float4* s4 = (const float4*)x;
            for (; idx < n8; idx += stride) {
                float4 a = s4[idx * 2], b = s4[idx * 2 + 1];
                uint4 o;
                o.x = (unsigned int)f2bf(a.x) | ((unsigned int)f2bf(a.y) << 16);
                o.y = (unsigned int)f2bf(a.z) | ((unsigned int)f2bf(a.w) << 16);
                o.z = (unsigned int)f2bf(b.x) | ((unsigned int)f2bf(b.y) << 16);
                o.w = (unsigned int)f2bf(b.z) | ((unsigned int)f2bf(b.w) << 16);
                d4[idx] = o;
            }
        }
        return;
    }
    // ---- pfill part: rec = (dst & (PNODES-1)) << 20 | src ----
    int base = blockIdx.x * 4096;
    for (int i = tid; i < np; i += 256) { cnt[i] = 0; loc[i] = 0; }
    __syncthreads();
    int pk[16]; unsigned int rec[16];
#pragma unroll
    for (int k = 0; k < 16; ++k) {
        int e = base + k * 256 + tid;
        if (e < E) {
            int d = dst[e];
            pk[k] = d >> PSH;
            rec[k] = ((unsigned int)(d & (PNODES - 1)) << 20) | (unsigned int)src[e];
            atomicAdd(&cnt[pk[k]], 1);
        } else pk[k] = -1;
    }
    __syncthreads();
    for (int i = tid; i < np; i += 256)
        if (cnt[i]) gb[i] = atomicAdd(&pcursor[i * CURPAD], cnt[i]);
    __syncthreads();
#pragma unroll
    for (int k = 0; k < 16; ++k) {
        if (pk[k] >= 0) {
            int off = atomicAdd(&loc[pk[k]], 1);
            barr[gb[pk[k]] + off] = rec[k];
        }
    }
}

// Block per partition (PNODES=256): LDS counting sort -> csr + row_start.
__global__ __launch_bounds__(256) void k_psort(const unsigned int* __restrict__ barr,
        const int* __restrict__ pstart, int* __restrict__ csr,
        int* __restrict__ row_start, int n, int np, int E) {
    __shared__ int hist[PNODES], curs[PNODES], tsum[256];
    int tid = threadIdx.x;
    int p = blockIdx.x;
    int e0 = pstart[p], e1 = pstart[p + 1];
    int node0 = p << PSH;
    hist[tid] = 0;
    __syncthreads();
    for (int t = e0 + tid; t < e1; t += 256)
        atomicAdd(&hist[barr[t] >> 20], 1);
    __syncthreads();
    int v = hist[tid];
    tsum[tid] = v; __syncthreads();
    for (int o = 1; o < 256; o <<= 1) {
        int u = (tid >= o) ? tsum[tid - o] : 0;
        __syncthreads(); tsum[tid] += u; __syncthreads();
    }
    int ex = tsum[tid] - v;
    curs[tid] = ex;
    int nd = node0 + tid;
    if (nd < n) row_start[nd] = e0 + ex;
    if (p == np - 1 && tid == 0) row_start[n] = E;
    __syncthreads();
    for (int t = e0 + tid; t < e1; t += 256) {
        unsigned int rec = barr[t];
        int pos = atomicAdd(&curs[rec >> 20], 1);
        csr[e0 + pos] = (int)(rec & 0xFFFFF);
    }
}

// ---- aggregation 0: bf16 gather on xb rows (128B), 4-deep batches -------
__global__ __launch_bounds__(256) void k_agg0(const u16* __restrict__ xb,
        const int* __restrict__ rs, const int* __restrict__ csr,
        u16* __restrict__ agg, int n) {
    int i = blockIdx.x * 4 + (threadIdx.x >> 6);
    if (i >= n) return;
    int lane = threadIdx.x & 63;
    int slot = lane >> 4, cp = lane & 15;   // xb row = 128B = 16 x uint2
    const unsigned int* x32 = (const unsigned int*)xb;
    int b = rs[i], e = rs[i + 1];
    float acc[4] = {0.f, 0.f, 0.f, 0.f};
    int t = b + slot;
    for (; t + 12 < e; t += 16) {
        int j0 = csr[t], j1 = csr[t + 4], j2 = csr[t + 8], j3 = csr[t + 12];
        uint2 w0 = *((const uint2*)(x32 + (long)j0 * 32) + cp);
        uint2 w1 = *((const uint2*)(x32 + (long)j1 * 32) + cp);
        uint2 w2 = *((const uint2*)(x32 + (long)j2 * 32) + cp);
        uint2 w3 = *((const uint2*)(x32 + (long)j3 * 32) + cp);
        acc[0] += lo16(w0.x) + lo16(w1.x); acc[1] += hi16(w0.x) + hi16(w1.x);
        acc[2] += lo16(w0.y) + lo16(w1.y); acc[3] += hi16(w0.y) + hi16(w1.y);
        acc[0] += lo16(w2.x) + lo16(w3.x); acc[1] += hi16(w2.x) + hi16(w3.x);
        acc[2] += lo16(w2.y) + lo16(w3.y); acc[3] += hi16(w2.y) + hi16(w3.y);
    }
    for (; t < e; t += 4) {
        int j0 = csr[t];
        uint2 w0 = *((const uint2*)(x32 + (long)j0 * 32) + cp);
        acc[0] += lo16(w0.x); acc[1] += hi16(w0.x);
        acc[2] += lo16(w0.y); acc[3] += hi16(w0.y);
    }
#pragma unroll
    for (int k = 0; k < 4; ++k) {
        acc[k] += __shfl_xor(acc[k], 16);
        acc[k] += __shfl_xor(acc[k], 32);
    }
    if (slot == 0) {
        uint2 o;
        o.x = (unsigned int)f2bf(acc[0]) | ((unsigned int)f2bf(acc[1]) << 16);
        o.y = (unsigned int)f2bf(acc[2]) | ((unsigned int)f2bf(acc[3]) << 16);
        *((uint2*)((unsigned int*)agg + (long)i * 32) + cp) = o;
    }
}

// ---- y0p = relu(bn0(y0)) materialized IN-PLACE (bf16), streaming --------
__global__ __launch_bounds__(256) void k_y0p(unsigned int* __restrict__ y0,
        const float* __restrict__ sc, const float* __restrict__ sh, long nq) {
    long idx = (long)blockIdx.x * 256 + threadIdx.x;
    int colq = threadIdx.x & 15;
    float s8[8], h8[8];
#pragma unroll
    for (int j = 0; j < 8; ++j) { s8[j] = sc[colq * 8 + j]; h8[j] = sh[colq * 8 + j]; }
    long stride = (long)gridDim.x * 256;
    uint4* p = (uint4*)y0;
    for (; idx < nq; idx += stride) {
        uint4 w = p[idx];
        unsigned int r[4] = {w.x, w.y, w.z, w.w};
        uint4 o;
        unsigned int* po = (unsigned int*)&o;
#pragma unroll
        for (int d = 0; d < 4; ++d) {
            float a = fmaxf(lo16(r[d]) * s8[2 * d]     + h8[2 * d],     0.f);
            float b = fmaxf(hi16(r[d]) * s8[2 * d + 1] + h8[2 * d + 1], 0.f);
            po[d] = (unsigned int)f2bf(a) | ((unsigned int)f2bf(b) << 16);
        }
        p[idx] = o;
    }
}

// ------- aggregation 1: pure bf16 gather, 4-deep batches -----------------
__global__ __launch_bounds__(256) void k_agg1(const u16* __restrict__ y0p,
        const int* __restrict__ rs, const int* __restrict__ csr,
        u16* __restrict__ agg, int n) {
    int i = blockIdx.x * 4 + (threadIdx.x >> 6);
    if (i >= n) return;
    int lane = threadIdx.x & 63;
    int slot = lane >> 4, cp = lane & 15;   // y0p row = 256B = 16 x uint4
    const unsigned int* y32 = (const unsigned int*)y0p;
    int b = rs[i], e = rs[i + 1];
    float acc[8] = {0.f, 0.f, 0.f, 0.f, 0.f, 0.f, 0.f, 0.f};
    int t = b + slot;
    for (; t + 12 < e; t += 16) {
        int j0 = csr[t], j1 = csr[t + 4], j2 = csr[t + 8], j3 = csr[t + 12];
        uint4 w0 = *((const uint4*)(y32 + (long)j0 * 64) + cp);
        uint4 w1 = *((const uint4*)(y32 + (long)j1 * 64) + cp);
        uint4 w2 = *((const uint4*)(y32 + (long)j2 * 64) + cp);
        uint4 w3 = *((const uint4*)(y32 + (long)j3 * 64) + cp);
        acc8(acc, w0); acc8(acc, w1); acc8(acc, w2); acc8(acc, w3);
    }
    for (; t < e; t += 4) {
        int j0 = csr[t];
        uint4 w0 = *((const uint4*)(y32 + (long)j0 * 64) + cp);
        acc8(acc, w0);
    }
#pragma unroll
    for (int k = 0; k < 8; ++k) {
        acc[k] += __shfl_xor(acc[k], 16);
        acc[k] += __shfl_xor(acc[k], 32);
    }
    if (slot == 0) {
        uint4 o;
        o.x = (unsigned int)f2bf(acc[0]) | ((unsigned int)f2bf(acc[1]) << 16);
        o.y = (unsigned int)f2bf(acc[2]) | ((unsigned int)f2bf(acc[3]) << 16);
        o.z = (unsigned int)f2bf(acc[4]) | ((unsigned int)f2bf(acc[5]) << 16);
        o.w = (unsigned int)f2bf(acc[6]) | ((unsigned int)f2bf(acc[7]) << 16);
        *((uint4*)((unsigned int*)agg + (long)i * 64) + cp) = o;
    }
}

// ------ GEMM0 (direct-global, persistent): y0 = [xb|agg0] @ W0^T ----------
template<bool BF>
__device__ __forceinline__ void gemm0_impl(const u16* xb, const u16* agg,
                                           const void* Wr, const void* Wn,
                                           u16* y0, float* sumP, float* sqP,
                                           int n, int nch) {
    int tid = threadIdx.x;
    int wave = tid >> 6, lane = tid & 63, lr = lane & 15, q = lane >> 4;

    short8 wf[2][4];
#pragma unroll
    for (int i = 0; i < 2; ++i) {
        int c = (2 * wave + i) * 16 + lr;
#pragma unroll
        for (int ks = 0; ks < 4; ++ks) {
            const void* W = (ks < 2) ? Wr : Wn;
            wf[i][ks] = ld8<BF>(W, (long)c * CIN + (ks & 1) * 32 + q * 8);
        }
    }

    float st[2] = {0.f, 0.f}, sq[2] = {0.f, 0.f};
    for (int ch = blockIdx.x; ch < nch; ch += gridDim.x) {
        long chunk0 = (long)ch * 64;
#pragma unroll
        for (int t = 0; t < 4; ++t) {
            long rg = chunk0 + t * 16 + lr; if (rg > n - 1) rg = n - 1;
            short8 a[4];
#pragma unroll
            for (int ks = 0; ks < 2; ++ks)
                a[ks] = *(const short8*)(xb + rg * CIN + ks * 32 + q * 8);
#pragma unroll
            for (int ks = 0; ks < 2; ++ks)
                a[2 + ks] = *(const short8*)(agg + rg * CIN + ks * 32 + q * 8);
#pragma unroll
            for (int i = 0; i < 2; ++i) {
                f32x4 acc = {0.f, 0.f, 0.f, 0.f};
#pragma unroll
                for (int ks = 0; ks < 4; ++ks)
                    acc = __builtin_amdgcn_mfma_f32_16x16x32_bf16(a[ks], wf[i][ks], acc, 0, 0, 0);
                int c = (2 * wave + i) * 16 + lr;
#pragma unroll
                for (int r = 0; r < 4; ++r) {
                    long row = chunk0 + t * 16 + q * 4 + r;
                    if (row < n) {
                        y0[row * COUT + c] = f2bf(acc[r]);   // b0 cancels in BN
                        st[i] += acc[r]; sq[i] += acc[r] * acc[r];
                    }
                }
            }
        }
    }
#pragma unroll
    for (int i = 0; i < 2; ++i) {
        st[i] += __shfl_xor(st[i], 16); st[i] += __shfl_xor(st[i], 32);
        sq[i] += __shfl_xor(sq[i], 16); sq[i] += __shfl_xor(sq[i], 32);
    }
    if (q == 0) {
#pragma unroll
        for (int i = 0; i < 2; ++i) {
            int c = (2 * wave + i) * 16 + lr;
            atomicAdd(&sumP[c * SPAD], st[i]);
            atomicAdd(&sqP[c * SPAD], sq[i]);
        }
    }
}

__global__ __launch_bounds__(256) void k_gemm0(const int* __restrict__ flag,
        const u16* __restrict__ xb, const u16* __restrict__ agg,
        const void* Wr, const void* Wn,
        u16* __restrict__ y0, float* __restrict__ sumP, float* __restrict__ sqP,
        int n, int nch) {
    if (*flag) gemm0_impl<true >(xb, agg, Wr, Wn, y0, sumP, sqP, n, nch);
    else       gemm0_impl<false>(xb, agg, Wr, Wn, y0, sumP, sqP, n, nch);
}

// ------ GEMM1 (LDS-staged + reg-prefetch): y1 = [y0p|agg1] @ W1^T ---------
template<bool BF>
__device__ __forceinline__ void gemm1_impl(const u16* y0p, const u16* agg,
                                           const void* Wr, const void* Wn,
                                           u16* y1, float* sumP, float* sqP,
                                           int n, int nch, u16* lds) {
    const int ST = 258;
    int tid = threadIdx.x;
    int wave = tid >> 6, lane = tid & 63, lr = lane & 15, q = lane >> 4;

    short8 wf[2][8];
#pragma unroll
    for (int i = 0; i < 2; ++i) {
        int c = (2 * wave + i) * 16 + lr;
#pragma unroll
        for (int ks = 0; ks < 8; ++ks) {
            const void* W = (ks < 4) ? Wr : Wn;
            wf[i][ks] = ld8<BF>(W, (long)c * COUT + (ks & 3) * 32 + q * 8);
        }
    }

    const int rowy = tid >> 4, wy = tid & 15;   // 128-wide rows: 4/thread
    short8 ry[4], rag[4];
    auto regload = [&](long chunk0) {
#pragma unroll
        for (int i = 0; i < 4; ++i) {
            long rg = chunk0 + rowy + i * 16; if (rg > n - 1) rg = n - 1;
            ry[i]  = *(const short8*)(y0p + rg * COUT + wy * 8);
            rag[i] = *(const short8*)(agg + rg * COUT + wy * 8);
        }
    };

    float st[2] = {0.f, 0.f}, sq[2] = {0.f, 0.f};
    int ch = blockIdx.x;
    if (ch < nch) regload((long)ch * 64);
    for (; ch < nch; ch += gridDim.x) {
        long chunk0 = (long)ch * 64;
        __syncthreads();
#pragma unroll
        for (int i = 0; i < 4; ++i) {
            *(short8*)(lds + (rowy + i * 16) * ST + wy * 8) = ry[i];
            *(short8*)(lds + (rowy + i * 16) * ST + 128 + wy * 8) = rag[i];
        }
        __syncthreads();
        long nxt = (long)ch + gridDim.x;
        if (nxt < nch) regload(nxt * 64);      // T14: prefetch next chunk

#pragma unroll
        for (int t = 0; t < 4; ++t) {
            short8 a[8];
#pragma unroll
            for (int ks = 0; ks < 8; ++ks)
                a[ks] = *(const short8*)(lds + (t * 16 + lr) * ST + ks * 32 + q * 8);
#pragma unroll
            for (int i = 0; i < 2; ++i) {
                f32x4 acc = {0.f, 0.f, 0.f, 0.f};
#pragma unroll
                for (int ks = 0; ks < 8; ++ks)
                    acc = __builtin_amdgcn_mfma_f32_16x16x32_bf16(a[ks], wf[i][ks], acc, 0, 0, 0);
                int c = (2 * wave + i) * 16 + lr;
#pragma unroll
                for (int r = 0; r < 4; ++r) {
                    long row = chunk0 + t * 16 + q * 4 + r;
                    if (row < n) {
                        y1[row * COUT + c] = f2bf(acc[r]);   // b1 cancels in BN
                        st[i] += acc[r]; sq[i] += acc[r] * acc[r];
                    }
                }
            }
        }
    }
#pragma unroll
    for (int i = 0; i < 2; ++i) {
        st[i] += __shfl_xor(st[i], 16); st[i] += __shfl_xor(st[i], 32);
        sq[i] += __shfl_xor(sq[i], 16); sq[i] += __shfl_xor(sq[i], 32);
    }
    if (q == 0) {
#pragma unroll
        for (int i = 0; i < 2; ++i) {
            int c = (2 * wave + i) * 16 + lr;
            atomicAdd(&sumP[c * SPAD], st[i]);
            atomicAdd(&sqP[c * SPAD], sq[i]);
        }
    }
}

__global__ __launch_bounds__(256) void k_gemm1(const int* __restrict__ flag,
        const u16* __restrict__ y0p, const u16* __restrict__ agg,
        const void* Wr, const void* Wn,
        u16* y1_bf /*=d_out*/, u16* y1_ws,
        float* __restrict__ sumP, float* __restrict__ sqP, int n, int nch) {
    __shared__ u16 lds[64 * 258];
    u16* y1 = *flag ? y1_bf : y1_ws;
    if (*flag) gemm1_impl<true >(y0p, agg, Wr, Wn, y1, sumP, sqP, n, nch, lds);
    else       gemm1_impl<false>(y0p, agg, Wr, Wn, y1, sumP, sqP, n, nch, lds);
}

// ---------------- BN finalize (reads line-padded stats) ----------------
__global__ void k_bnfin(const int* __restrict__ flag,
                        const float* __restrict__ sumP, const float* __restrict__ sqP,
                        const void* g, const void* be,
                        float* __restrict__ scale, float* __restrict__ shift, int n) {
    int c = threadIdx.x;
    bool bf = (*flag != 0);
    float inv = 1.f / (float)n;
    float mu = sumP[c * SPAD] * inv;
    float var = fmaxf(sqP[c * SPAD] * inv - mu * mu, 0.f);
    float gv = bf ? bf2f(((const u16*)g)[c]) : ((const float*)g)[c];
    float bv = bf ? bf2f(((const u16*)be)[c]) : ((const float*)be)[c];
    float sc = gv * rsqrtf(var + BN_EPS);
    scale[c] = sc;
    shift[c] = bv - mu * sc;
}

// -------- final: out = relu(bn1(y1) + xb@Wlin^T + blin) -------------------
template<bool BF>
__device__ __forceinline__ void final_impl(const u16* xb, const u16* y1,
                                           const void* Wlin, const void* blin,
                                           const float* sc, const float* sh,
                                           void* out, int n, int nch, u16* lds) {
    const int ST = 130;
    int tid = threadIdx.x;
    int wave = tid >> 6, lane = tid & 63, lr = lane & 15, q = lane >> 4;

    short8 wf[2][2];
    float blc[2], scc[2], shc[2];
#pragma unroll
    for (int i = 0; i < 2; ++i) {
        int c = (2 * wave + i) * 16 + lr;
#pragma unroll
        for (int ks = 0; ks < 2; ++ks)
            wf[i][ks] = ld8<BF>(Wlin, (long)c * CIN + ks * 32 + q * 8);
        blc[i] = ldf<BF>(blin, c);
        scc[i] = sc[c]; shc[i] = sh[c];
    }

    const int rowy = tid >> 4, wy = tid & 15;
    short8 ry[4];

    auto regload = [&](long chunk0) {
#pragma unroll
        for (int i = 0; i < 4; ++i) {
            long rg = chunk0 + rowy + i * 16; if (rg > n - 1) rg = n - 1;
            ry[i] = *(const short8*)(y1 + rg * COUT + wy * 8);
        }
    };

    int ch = blockIdx.x;
    if (ch < nch) regload((long)ch * 64);
    for (; ch < nch; ch += gridDim.x) {
        long chunk0 = (long)ch * 64;
        __syncthreads();
#pragma unroll
        for (int i = 0; i < 4; ++i)
            *(short8*)(lds + (rowy + i * 16) * ST + wy * 8) = ry[i];
        __syncthreads();
        long nxt = (long)ch + gridDim.x;
        if (nxt < nch) regload(nxt * 64);

#pragma unroll
        for (int t = 0; t < 4; ++t) {
            long rg = chunk0 + t * 16 + lr; if (rg > n - 1) rg = n - 1;
            short8 a[2];
#pragma unroll
            for (int ks = 0; ks < 2; ++ks)
                a[ks] = *(const short8*)(xb + rg * CIN + ks * 32 + q * 8);
#pragma unroll
            for (int i = 0; i < 2; ++i) {
                f32x4 acc = {0.f, 0.f, 0.f, 0.f};
                acc = __builtin_amdgcn_mfma_f32_16x16x32_bf16(a[0], wf[i][0], acc, 0, 0, 0);
                acc = __builtin_amdgcn_mfma_f32_16x16x32_bf16(a[1], wf[i][1], acc, 0, 0, 0);
                int c = (2 * wave + i) * 16 + lr;
#pragma unroll
                for (int r = 0; r < 4; ++r) {
                    long row = chunk0 + t * 16 + q * 4 + r;
                    if (row < n) {
                        float yv = bf2f(lds[(t * 16 + q * 4 + r) * ST + c]);
                        float v = acc[r] + blc[i] + yv * scc[i] + shc[i];
                        v = fmaxf(v, 0.f);
                        if (BF) ((u16*)out)[row * COUT + c] = f2bf(v);
                        else    ((float*)out)[row * COUT + c] = v;
                    }
                }
            }
        }
    }
}

__global__ __launch_bounds__(256) void k_final(const int* __restrict__ flag,
        const u16* __restrict__ xb, const void* Wlin, const void* blin,
        const u16* y1_bf /*=d_out*/, const u16* y1_ws,
        const float* __restrict__ sc, const float* __restrict__ sh,
        void* out, int n, int nch) {
    __shared__ u16 lds[64 * 130];
    const u16* y1 = *flag ? y1_bf : y1_ws;
    if (*flag) final_impl<true >(xb, y1, Wlin, blin, sc, sh, out, n, nch, lds);
    else       final_impl<false>(xb, y1, Wlin, blin, sc, sh, out, n, nch, lds);
}

extern "C" void kernel_launch(void* const* d_in, const int* in_sizes, int n_in,
                              void* d_out, int out_size, void* d_ws, size_t ws_size,
                              hipStream_t stream) {
    (void)n_in; (void)out_size; (void)ws_size;
    const void* x    = d_in[0];
    const int*  ei   = (const int*)d_in[1];
    const void* Wr0  = d_in[2];
    const void* Wn0  = d_in[3];
    /* b0 dropped: BN-invariant */
    const void* g0   = d_in[5];
    const void* be0  = d_in[6];
    const void* Wr1  = d_in[7];
    const void* Wn1  = d_in[8];
    /* b1 dropped */
    const void* g1   = d_in[10];
    const void* be1  = d_in[11];
    const void* Wlin = d_in[12];
    const void* blin = d_in[13];

    const int N = in_sizes[0] / CIN;
    const int E = in_sizes[1] / 2;
    const int* src = ei;
    const int* dst = ei + E;
    const int NP = (N + PNODES - 1) >> PSH;   // <= MAXP for N <= 131072

    // ---- workspace carve (256B aligned) ----
    char* base = (char*)d_ws;
    size_t off = 0;
    auto carve = [&](size_t bytes) -> void* {
        void* p = base + off;
        off = (off + bytes + 255) & ~(size_t)255;
        return p;
    };
    int*   flag      = (int*)carve(256);
    int*   pcount    = (int*)carve(MAXP * PCPAD * sizeof(int));
    int*   pstart    = (int*)carve((MAXP + 1) * sizeof(int));
    int*   pcursor   = (int*)carve(MAXP * CURPAD * sizeof(int));
    float* statsP    = (float*)carve(4 * 128 * SPAD * sizeof(float));
    float* scsh      = (float*)carve(512 * sizeof(float));
    int*   row_start = (int*)carve((size_t)(N + 1) * sizeof(int));
    unsigned int* barr = (unsigned int*)carve((size_t)E * sizeof(int));
    int*   csr       = (int*)carve((size_t)E * sizeof(int));
    u16*   xb        = (u16*)carve((size_t)N * CIN * sizeof(u16));
    u16*   aggu      = (u16*)carve((size_t)N * COUT * sizeof(u16));
    u16*   y0        = (u16*)carve((size_t)N * COUT * sizeof(u16));
    u16*   y1_ws     = (u16*)carve((size_t)N * COUT * sizeof(u16));

    float* sum0P = statsP;
    float* sq0P  = statsP + 128 * SPAD;
    float* sum1P = statsP + 256 * SPAD;
    float* sq1P  = statsP + 384 * SPAD;

    hipMemsetAsync(pcount, 0, MAXP * PCPAD * sizeof(int), stream);
    hipMemsetAsync(statsP, 0, 4 * 128 * SPAD * sizeof(float), stream);

    const int nwb = (N + 3) / 4;        // wave-per-node agg blocks
    const int nch = (N + 63) / 64;      // 64-row chunks
    const int ntl = (E + 4095) / 4096;  // pfill tiles
    const int G   = nch < 512 ? nch : 512;   // persistent grid (R21: 1024->512)
    const long nq = (long)N * 16;       // y0 uint4-quads
    const long n8 = (long)N * CIN / 8;  // xb 8-elem groups
    int g2 = (int)((nq + 255) / 256); if (g2 > 2048) g2 = 2048;
    int g3 = (int)((n8 + 255) / 256); if (g3 > 1024) g3 = 1024;

    k_prep<<<257, 256, 0, stream>>>((const unsigned int*)x, flag, dst, pcount, E, NP);
    k_pscan<<<1, MAXP, 0, stream>>>(pcount, pstart, pcursor, NP, E);
    k_fill2<<<ntl + g3, 256, 0, stream>>>(src, dst, pcursor, barr, E, NP, ntl,
                                          flag, x, xb, n8);
    k_psort<<<NP, 256, 0, stream>>>(barr, pstart, csr, row_start, N, NP, E);

    k_agg0 <<<nwb, 256, 0, stream>>>(xb, row_start, csr, aggu, N);
    k_gemm0<<<G, 256, 0, stream>>>(flag, xb, aggu, Wr0, Wn0, y0,
                                   sum0P, sq0P, N, nch);
    k_bnfin<<<1, 128, 0, stream>>>(flag, sum0P, sq0P, g0, be0,
                                   scsh, scsh + 128, N);

    k_y0p<<<g2, 256, 0, stream>>>((unsigned int*)y0, scsh, scsh + 128, nq);

    k_agg1 <<<nwb, 256, 0, stream>>>(y0, row_start, csr, aggu, N);
    k_gemm1<<<G, 256, 0, stream>>>(flag, y0, aggu, Wr1, Wn1,
                                   (u16*)d_out, y1_ws, sum1P, sq1P, N, nch);
    k_bnfin<<<1, 128, 0, stream>>>(flag, sum1P, sq1P, g1, be1,
                                   scsh + 256, scsh + 384, N);

    k_final<<<G, 256, 0, stream>>>(flag, xb, Wlin, blin,
                                   (const u16*)d_out, y1_ws,
                                   scsh + 256, scsh + 384, d_out, N, nch);
}